// Round 1
// baseline (825.984 us; speedup 1.0000x reference)
//
#include <hip/hip_runtime.h>

#define N_NODES 20000
#define S_COLS  4096
#define E_EDGES 640000
#define D_DIM   256

typedef unsigned short bf16_t;
typedef __attribute__((ext_vector_type(8))) short short8;
typedef __attribute__((ext_vector_type(4))) float f32x4;

__device__ __forceinline__ float bf2f(bf16_t u) {
    union { unsigned int i; float f; } v; v.i = ((unsigned int)u) << 16; return v.f;
}
__device__ __forceinline__ bf16_t f2bf(float x) {   // round-to-nearest-even
    union { float f; unsigned int i; } v; v.f = x;
    unsigned int r = v.i + 0x7FFF + ((v.i >> 16) & 1);
    return (bf16_t)(r >> 16);
}
__device__ __forceinline__ float lo_bf(unsigned int u) {
    union { unsigned int i; float f; } v; v.i = u << 16; return v.f;
}
__device__ __forceinline__ float hi_bf(unsigned int u) {
    union { unsigned int i; float f; } v; v.i = u & 0xFFFF0000u; return v.f;
}
__device__ __forceinline__ unsigned int pack_bf(float a, float b) {
    return (unsigned int)f2bf(a) | ((unsigned int)f2bf(b) << 16);
}

// ---------------------------------------------------------------------------
// K1: h0[i] = (cnt*b2 + fsum @ w2) / max(cnt,1); fsum = 16-dim feature sum
// over nonzero column indices. Block-per-row (PROVEN round-3/4 version —
// the wave-per-row variant spilled to scratch: VGPR cap 64, 2.7 GB of
// scratch traffic, 1746 us. Keep per-thread state small.)
// ---------------------------------------------------------------------------
__global__ void h0_kernel(const float* __restrict__ init_m,
                          const float* __restrict__ w1, const float* __restrict__ b1,
                          const float* __restrict__ w2, const float* __restrict__ b2,
                          bf16_t* __restrict__ h) {
    __shared__ float w2s[16][256];
    __shared__ int   list[1024];
    __shared__ int   count;
    __shared__ float fred[4][16];
    __shared__ float ftot[16];
    int i = blockIdx.x;
    int t = threadIdx.x;

#pragma unroll
    for (int k = 0; k < 16; ++k) w2s[k][t] = w2[k * D_DIM + t];
    if (t == 0) count = 0;
    __syncthreads();

    const float4* rowp = (const float4*)(init_m + (size_t)i * S_COLS);
#pragma unroll
    for (int p = 0; p < 4; ++p) {
        int v4 = t + p * 256;
        float4 v = rowp[v4];
        int jbase = v4 * 4;
        if (v.x != 0.f) { int idx = atomicAdd(&count, 1); list[idx] = jbase;     }
        if (v.y != 0.f) { int idx = atomicAdd(&count, 1); list[idx] = jbase + 1; }
        if (v.z != 0.f) { int idx = atomicAdd(&count, 1); list[idx] = jbase + 2; }
        if (v.w != 0.f) { int idx = atomicAdd(&count, 1); list[idx] = jbase + 3; }
    }
    __syncthreads();
    int cnt = count;

    float lw1[16], lb1[16];
#pragma unroll
    for (int k = 0; k < 16; ++k) { lw1[k] = w1[k]; lb1[k] = b1[k]; }
    float f[16] = {};
    for (int q = t; q < cnt; q += 256) {
        float jf = (float)list[q];
#pragma unroll
        for (int k = 0; k < 16; ++k)
            f[k] += fmaxf(jf * lw1[k] + lb1[k], 0.f);
    }
#pragma unroll
    for (int k = 0; k < 16; ++k) {
#pragma unroll
        for (int off = 32; off > 0; off >>= 1)
            f[k] += __shfl_xor(f[k], off, 64);
    }
    int wave = t >> 6, lane = t & 63;
    if (lane == 0) {
#pragma unroll
        for (int k = 0; k < 16; ++k) fred[wave][k] = f[k];
    }
    __syncthreads();
    if (t < 16) ftot[t] = fred[0][t] + fred[1][t] + fred[2][t] + fred[3][t];
    __syncthreads();

    float cf = (float)cnt;
    float acc = cf * b2[t];
#pragma unroll
    for (int k = 0; k < 16; ++k) acc += ftot[k] * w2s[k][t];
    h[(size_t)i * D_DIM + t] = f2bf(acc / fmaxf(cf, 1.f));
}

// ---------------------------------------------------------------------------
// CSC build (counting sort by destination col)
// ---------------------------------------------------------------------------
__global__ void count_kernel(const int* __restrict__ eidx, int* __restrict__ cnt) {
    int e = blockIdx.x * 256 + threadIdx.x;
    if (e < E_EDGES) atomicAdd(&cnt[eidx[E_EDGES + e]], 1);
}

__global__ void scan_kernel(const int* __restrict__ cnt, int* __restrict__ offs,
                            int* __restrict__ cur) {
    __shared__ int sdata[1024];
    int t = threadIdx.x;
    int base = t * 20;
    int vals[20];
    int local = 0;
#pragma unroll
    for (int k = 0; k < 20; ++k) {
        int idx = base + k;
        int v = (idx < N_NODES) ? cnt[idx] : 0;
        vals[k] = local;
        local += v;
    }
    sdata[t] = local;
    __syncthreads();
    for (int off = 1; off < 1024; off <<= 1) {
        int v = (t >= off) ? sdata[t - off] : 0;
        __syncthreads();
        sdata[t] += v;
        __syncthreads();
    }
    int prefix = (t == 0) ? 0 : sdata[t - 1];
#pragma unroll
    for (int k = 0; k < 20; ++k) {
        int idx = base + k;
        if (idx < N_NODES) {
            int o = prefix + vals[k];
            offs[idx] = o;
            cur[idx]  = o;
        }
    }
    if (t == 1023) offs[N_NODES] = sdata[1023];
}

__global__ void fill_kernel(const int* __restrict__ eidx, const float* __restrict__ attr,
                            int* __restrict__ cur, int* __restrict__ src_s,
                            float* __restrict__ attr_s) {
    int e = blockIdx.x * 256 + threadIdx.x;
    if (e < E_EDGES) {
        int r = eidx[e];
        int c = eidx[E_EDGES + e];
        int pos = atomicAdd(&cur[c], 1);
        src_s[pos]  = r;
        attr_s[pos] = attr[e];
    }
}

// ---------------------------------------------------------------------------
// W preprocessing: transpose + fp32 -> bf16 hi/lo split
// ---------------------------------------------------------------------------
__global__ void wsplit_kernel(const float* __restrict__ W,
                              bf16_t* __restrict__ Wt_hi, bf16_t* __restrict__ Wt_lo) {
    int k = blockIdx.x;
    int n = threadIdx.x;
    float w = W[k * D_DIM + n];
    bf16_t hi = f2bf(w);
    bf16_t lo = f2bf(w - bf2f(hi));
    Wt_hi[n * D_DIM + k] = hi;
    Wt_lo[n * D_DIM + k] = lo;
}

// ---------------------------------------------------------------------------
// K3: t = h @ W, bf16 in/out, W = hi+lo planes (n-major). MFMA 16x16x32.
// ---------------------------------------------------------------------------
__global__ void gemm_mfma_kernel(const bf16_t* __restrict__ h,
                                 const bf16_t* __restrict__ Wt_hi,
                                 const bf16_t* __restrict__ Wt_lo,
                                 bf16_t* __restrict__ t) {
    int w    = threadIdx.x >> 6;
    int lane = threadIdx.x & 63;
    int quad = lane >> 4;
    int id16 = lane & 15;
    int bm   = blockIdx.x * 64 + w * 16;
    int bn   = blockIdx.y * 64;

    f32x4 acc[4];
#pragma unroll
    for (int nt = 0; nt < 4; ++nt) acc[nt] = (f32x4){0.f, 0.f, 0.f, 0.f};

    const bf16_t* arow = h + (size_t)(bm + id16) * D_DIM;
#pragma unroll
    for (int k0 = 0; k0 < 256; k0 += 32) {
        short8 a = *(const short8*)(arow + k0 + quad * 8);
#pragma unroll
        for (int nt = 0; nt < 4; ++nt) {
            const bf16_t* brow = Wt_hi + (size_t)(bn + nt * 16 + id16) * D_DIM + k0 + quad * 8;
            const bf16_t* lrow = Wt_lo + (size_t)(bn + nt * 16 + id16) * D_DIM + k0 + quad * 8;
            short8 bh = *(const short8*)brow;
            short8 bl = *(const short8*)lrow;
            acc[nt] = __builtin_amdgcn_mfma_f32_16x16x32_bf16(a, bh, acc[nt], 0, 0, 0);
            acc[nt] = __builtin_amdgcn_mfma_f32_16x16x32_bf16(a, bl, acc[nt], 0, 0, 0);
        }
    }
#pragma unroll
    for (int nt = 0; nt < 4; ++nt) {
#pragma unroll
        for (int r = 0; r < 4; ++r) {
            int m = bm + quad * 4 + r;
            if (m < N_NODES)
                t[(size_t)m * D_DIM + bn + nt * 16 + id16] = f2bf(acc[nt][r]);
        }
    }
}

// ---------------------------------------------------------------------------
// K2: h_next[c] = relu( sum_{e into c} t[src[e]] * attr[e] )
// COLUMN-QUARTER-SPLIT: one wave per (dest, 64-col quarter). Each edge read
// is exactly one 128B L2 line; the per-quarter working set of t is 2.56 MB
// and fits a 4 MiB per-XCD L2 (full t = 10.24 MB does NOT — that was the
// mixed-L2/L3 latency regime of the previous version). Quarter-major block
// order (blocks 0..4999 -> cols 0..63, ...) keeps resident waves on ~one
// quarter at a time. Edge lists re-read 4x (~15 MB/layer extra, cheap).
// Inside the wave: 8 lanes x 16B per edge, 8 edges per u-step, 4-deep
// unroll -> 4 independent 16B loads in flight per lane. Padded slots read
// row 0 with a=0 (L1-hot, zero contribution).
// ---------------------------------------------------------------------------
__global__ void gather_relu_kernel(const bf16_t* __restrict__ t,
                                   const int* __restrict__ offs,
                                   const int* __restrict__ src_s,
                                   const float* __restrict__ attr_s,
                                   bf16_t* __restrict__ hdst, float* __restrict__ fdst) {
    int g    = (blockIdx.x * blockDim.x + threadIdx.x) >> 6;   // global wave id
    int lane = threadIdx.x & 63;
    int quarter = g / N_NODES;          // 0..3, quarter-major
    int wid     = g - quarter * N_NODES;
    if (quarter >= 4) return;
    int grp = lane >> 3;                // 8 groups of 8 lanes; one edge per group/step
    int l8  = lane & 7;                 // 8 lanes x 16B = 128B = one quarter row
    int e0 = offs[wid], e1 = offs[wid + 1];

    const bf16_t* tq = t + quarter * 64;

    float acc[8] = {};
    for (int base = e0; base < e1; base += 64) {
        int n = e1 - base; if (n > 64) n = 64;
        int   r_l = 0; float a_l = 0.f;
        if (lane < n) { r_l = src_s[base + lane]; a_l = attr_s[base + lane]; }
        int nn = (n + 31) & ~31;        // 32-edge granularity, pad slots contribute 0
        for (int q = 0; q < nn; q += 32) {
#pragma unroll
            for (int u = 0; u < 4; ++u) {
                int   sl = q + u * 8 + grp;
                int   r  = __shfl(r_l, sl, 64);
                float a  = __shfl(a_l, sl, 64);
                uint4 v  = ((const uint4*)(tq + (size_t)r * D_DIM))[l8];
                acc[0] += lo_bf(v.x) * a;  acc[1] += hi_bf(v.x) * a;
                acc[2] += lo_bf(v.y) * a;  acc[3] += hi_bf(v.y) * a;
                acc[4] += lo_bf(v.z) * a;  acc[5] += hi_bf(v.z) * a;
                acc[6] += lo_bf(v.w) * a;  acc[7] += hi_bf(v.w) * a;
            }
        }
    }
    // reduce the 8 edge-groups (same columns, different edges)
#pragma unroll
    for (int i = 0; i < 8; ++i) {
        acc[i] += __shfl_xor(acc[i], 8, 64);
        acc[i] += __shfl_xor(acc[i], 16, 64);
        acc[i] += __shfl_xor(acc[i], 32, 64);
    }

    if (grp == 0) {
#pragma unroll
        for (int i = 0; i < 8; ++i) acc[i] = fmaxf(acc[i], 0.f);
        if (hdst) {
            uint4 o;
            o.x = pack_bf(acc[0], acc[1]);
            o.y = pack_bf(acc[2], acc[3]);
            o.z = pack_bf(acc[4], acc[5]);
            o.w = pack_bf(acc[6], acc[7]);
            ((uint4*)(hdst + (size_t)wid * D_DIM + quarter * 64))[l8] = o;
        } else {
            float4 o0 = { acc[0], acc[1], acc[2], acc[3] };
            float4 o1 = { acc[4], acc[5], acc[6], acc[7] };
            float* dst = fdst + (size_t)wid * D_DIM + quarter * 64 + l8 * 8;
            *(float4*)dst       = o0;
            *(float4*)(dst + 4) = o1;
        }
    }
}

extern "C" void kernel_launch(void* const* d_in, const int* in_sizes, int n_in,
                              void* d_out, int out_size, void* d_ws, size_t ws_size,
                              hipStream_t stream) {
    const float* init_m = (const float*)d_in[0];
    const int*   eidx   = (const int*)  d_in[1];
    const float* attr   = (const float*)d_in[2];
    const float* w1     = (const float*)d_in[3];
    const float* b1     = (const float*)d_in[4];
    const float* w2     = (const float*)d_in[5];
    const float* b2     = (const float*)d_in[6];
    const float* Wm     = (const float*)d_in[7];
    float* out = (float*)d_out;

    // Workspace layout (bytes). hbuf/tbuf have 16KB slack for the GEMM
    // m-overread (rows 20000..20031; poison is finite bf16).
    char* ws = (char*)d_ws;
    bf16_t* hbuf   = (bf16_t*)ws;                        // 10,240,000 (+16K slack)
    bf16_t* tbuf   = (bf16_t*)(ws + 10256384);           // 10,240,000 (+16K slack)
    bf16_t* Wt_hi  = (bf16_t*)(ws + 20512768);           // 131,072
    bf16_t* Wt_lo  = (bf16_t*)(ws + 20643840);           // 131,072
    int*    cnt    = (int*)   (ws + 20774912);           // 80,000
    int*    offs   = (int*)   (ws + 20854912);           // 80,004
    int*    cur    = (int*)   (ws + 20934928);           // 80,000
    int*    src_s  = (int*)   (ws + 21014928);           // 2,560,000
    float*  attr_s = (float*) (ws + 23574928);           // 2,560,000

    // --- CSC build ---
    hipMemsetAsync(cnt, 0, (size_t)N_NODES * sizeof(int), stream);
    count_kernel<<<(E_EDGES + 255) / 256, 256, 0, stream>>>(eidx, cnt);
    scan_kernel<<<1, 1024, 0, stream>>>(cnt, offs, cur);
    fill_kernel<<<(E_EDGES + 255) / 256, 256, 0, stream>>>(eidx, attr, cur, src_s, attr_s);

    // --- W transpose + hi/lo split ---
    wsplit_kernel<<<D_DIM, D_DIM, 0, stream>>>(Wm, Wt_hi, Wt_lo);

    // --- Projection: block-per-row (no spill) ---
    h0_kernel<<<N_NODES, 256, 0, stream>>>(init_m, w1, b1, w2, b2, hbuf);

    // --- 3x GCN layer: t = h@W (MFMA), then h' = relu(gather(t)) ---
    dim3 ggrid((N_NODES * 4 * 64) / 256);   // 4 col-quarters x 20000 dests, 1 wave each
    dim3 mgrid((N_NODES + 63) / 64, 4);
    for (int it = 0; it < 3; ++it) {
        gemm_mfma_kernel<<<mgrid, 256, 0, stream>>>(hbuf, Wt_hi, Wt_lo, tbuf);
        if (it == 2)
            gather_relu_kernel<<<ggrid, 256, 0, stream>>>(tbuf, offs, src_s, attr_s,
                                                          (bf16_t*)nullptr, out);
        else
            gather_relu_kernel<<<ggrid, 256, 0, stream>>>(tbuf, offs, src_s, attr_s,
                                                          hbuf, (float*)nullptr);
    }
}

// Round 2
// 798.009 us; speedup vs baseline: 1.0351x; 1.0351x over previous
//
#include <hip/hip_runtime.h>

#define N_NODES 20000
#define S_COLS  4096
#define E_EDGES 640000
#define D_DIM   256

typedef unsigned short bf16_t;
typedef __attribute__((ext_vector_type(8))) short short8;
typedef __attribute__((ext_vector_type(4))) float f32x4;

__device__ __forceinline__ float bf2f(bf16_t u) {
    union { unsigned int i; float f; } v; v.i = ((unsigned int)u) << 16; return v.f;
}
__device__ __forceinline__ bf16_t f2bf(float x) {   // round-to-nearest-even
    union { float f; unsigned int i; } v; v.f = x;
    unsigned int r = v.i + 0x7FFF + ((v.i >> 16) & 1);
    return (bf16_t)(r >> 16);
}
__device__ __forceinline__ float lo_bf(unsigned int u) {
    union { unsigned int i; float f; } v; v.i = u << 16; return v.f;
}
__device__ __forceinline__ float hi_bf(unsigned int u) {
    union { unsigned int i; float f; } v; v.i = u & 0xFFFF0000u; return v.f;
}
__device__ __forceinline__ unsigned int pack_bf(float a, float b) {
    return (unsigned int)f2bf(a) | ((unsigned int)f2bf(b) << 16);
}

// ---------------------------------------------------------------------------
// MEGA front-end kernel: three independent jobs, blockIdx-partitioned.
//   blocks [0, N_NODES)             : h0 projection (block-per-row, proven)
//   blocks [N_NODES, N_NODES+2500)  : edge count (CSC histogram)
//   blocks [N_NODES+2500, +256)     : W transpose + fp32 -> bf16 hi/lo split
// count + wsplit hide under h0's 327 MB HBM read.
// ---------------------------------------------------------------------------
__global__ void mega_kernel(const float* __restrict__ init_m,
                            const float* __restrict__ w1, const float* __restrict__ b1,
                            const float* __restrict__ w2, const float* __restrict__ b2,
                            bf16_t* __restrict__ h,
                            const int* __restrict__ eidx, int* __restrict__ cnt,
                            const float* __restrict__ W,
                            bf16_t* __restrict__ Wt_hi, bf16_t* __restrict__ Wt_lo) {
    __shared__ float w2s[16][256];
    __shared__ int   list[1024];
    __shared__ int   count;
    __shared__ float fred[4][16];
    __shared__ float ftot[16];
    int b = blockIdx.x;
    int t = threadIdx.x;

    if (b >= N_NODES) {
        int bb = b - N_NODES;
        if (bb < 2500) {                       // ---- edge count ----
            int e = bb * 256 + t;
            atomicAdd(&cnt[eidx[E_EDGES + e]], 1);
        } else {                               // ---- wsplit ----
            int k = bb - 2500;                 // 0..255
            float w = W[k * D_DIM + t];
            bf16_t hi = f2bf(w);
            bf16_t lo = f2bf(w - bf2f(hi));
            Wt_hi[t * D_DIM + k] = hi;
            Wt_lo[t * D_DIM + k] = lo;
        }
        return;
    }

    // ---- h0: h0[i] = (cnt*b2 + fsum @ w2) / max(cnt,1) ----
    int i = b;
#pragma unroll
    for (int k = 0; k < 16; ++k) w2s[k][t] = w2[k * D_DIM + t];
    if (t == 0) count = 0;
    __syncthreads();

    const float4* rowp = (const float4*)(init_m + (size_t)i * S_COLS);
#pragma unroll
    for (int p = 0; p < 4; ++p) {
        int v4 = t + p * 256;
        float4 v = rowp[v4];
        int jbase = v4 * 4;
        if (v.x != 0.f) { int idx = atomicAdd(&count, 1); list[idx] = jbase;     }
        if (v.y != 0.f) { int idx = atomicAdd(&count, 1); list[idx] = jbase + 1; }
        if (v.z != 0.f) { int idx = atomicAdd(&count, 1); list[idx] = jbase + 2; }
        if (v.w != 0.f) { int idx = atomicAdd(&count, 1); list[idx] = jbase + 3; }
    }
    __syncthreads();
    int cn = count;

    float lw1[16], lb1[16];
#pragma unroll
    for (int k = 0; k < 16; ++k) { lw1[k] = w1[k]; lb1[k] = b1[k]; }
    float f[16] = {};
    for (int q = t; q < cn; q += 256) {
        float jf = (float)list[q];
#pragma unroll
        for (int k = 0; k < 16; ++k)
            f[k] += fmaxf(jf * lw1[k] + lb1[k], 0.f);
    }
#pragma unroll
    for (int k = 0; k < 16; ++k) {
#pragma unroll
        for (int off = 32; off > 0; off >>= 1)
            f[k] += __shfl_xor(f[k], off, 64);
    }
    int wave = t >> 6, lane = t & 63;
    if (lane == 0) {
#pragma unroll
        for (int k = 0; k < 16; ++k) fred[wave][k] = f[k];
    }
    __syncthreads();
    if (t < 16) ftot[t] = fred[0][t] + fred[1][t] + fred[2][t] + fred[3][t];
    __syncthreads();

    float cf = (float)cn;
    float acc = cf * b2[t];
#pragma unroll
    for (int k = 0; k < 16; ++k) acc += ftot[k] * w2s[k][t];
    h[(size_t)i * D_DIM + t] = f2bf(acc / fmaxf(cf, 1.f));
}

// ---------------------------------------------------------------------------
// CSC build: scan + fill (count lives in mega_kernel)
// ---------------------------------------------------------------------------
__global__ void scan_kernel(const int* __restrict__ cnt, int* __restrict__ offs,
                            int* __restrict__ cur) {
    __shared__ int sdata[1024];
    int t = threadIdx.x;
    int base = t * 20;
    int vals[20];
    int local = 0;
#pragma unroll
    for (int k = 0; k < 20; ++k) {
        int idx = base + k;
        int v = (idx < N_NODES) ? cnt[idx] : 0;
        vals[k] = local;
        local += v;
    }
    sdata[t] = local;
    __syncthreads();
    for (int off = 1; off < 1024; off <<= 1) {
        int v = (t >= off) ? sdata[t - off] : 0;
        __syncthreads();
        sdata[t] += v;
        __syncthreads();
    }
    int prefix = (t == 0) ? 0 : sdata[t - 1];
#pragma unroll
    for (int k = 0; k < 20; ++k) {
        int idx = base + k;
        if (idx < N_NODES) {
            int o = prefix + vals[k];
            offs[idx] = o;
            cur[idx]  = o;
        }
    }
    if (t == 1023) offs[N_NODES] = sdata[1023];
}

__global__ void fill_kernel(const int* __restrict__ eidx, const float* __restrict__ attr,
                            int* __restrict__ cur, int* __restrict__ src_s,
                            float* __restrict__ attr_s) {
    int e = blockIdx.x * 256 + threadIdx.x;
    if (e < E_EDGES) {
        int r = eidx[e];
        int c = eidx[E_EDGES + e];
        int pos = atomicAdd(&cur[c], 1);
        src_s[pos]  = r;
        attr_s[pos] = attr[e];
    }
}

// ---------------------------------------------------------------------------
// Gather (reference order: aggregation FIRST): g[c] = sum_{e into c} h[src[e]]*attr[e]
// One wave per dest; half-wave per edge, 16B loads, 8 loads in flight.
// No relu here (relu fused into the GEMM epilogue, matching reference).
// ---------------------------------------------------------------------------
__global__ void gather_kernel(const bf16_t* __restrict__ h,
                              const int* __restrict__ offs,
                              const int* __restrict__ src_s,
                              const float* __restrict__ attr_s,
                              bf16_t* __restrict__ g) {
    int wid  = (blockIdx.x * blockDim.x + threadIdx.x) >> 6;
    int lane = threadIdx.x & 63;
    if (wid >= N_NODES) return;
    int half = lane >> 5;
    int l32  = lane & 31;
    int e0 = offs[wid], e1 = offs[wid + 1];

    float acc[8] = {};
    for (int base = e0; base < e1; base += 64) {
        int n = e1 - base; if (n > 64) n = 64;
        int   r_l = 0; float a_l = 0.f;
        if (lane < n) { r_l = src_s[base + lane]; a_l = attr_s[base + lane]; }
        int nn = (n + 15) & ~15;            // pad to 8 pair-iterations
        for (int q = 0; q < nn; q += 16) {
#pragma unroll
            for (int u = 0; u < 8; ++u) {
                int   sl = q + 2 * u + half;
                int   r  = __shfl(r_l, sl, 64);
                float a  = __shfl(a_l, sl, 64);
                uint4 v  = ((const uint4*)(h + (size_t)r * D_DIM))[l32];
                acc[0] += lo_bf(v.x) * a;  acc[1] += hi_bf(v.x) * a;
                acc[2] += lo_bf(v.y) * a;  acc[3] += hi_bf(v.y) * a;
                acc[4] += lo_bf(v.z) * a;  acc[5] += hi_bf(v.z) * a;
                acc[6] += lo_bf(v.w) * a;  acc[7] += hi_bf(v.w) * a;
            }
        }
    }
#pragma unroll
    for (int i = 0; i < 8; ++i) acc[i] += __shfl_xor(acc[i], 32, 64);

    if (half == 0) {
        uint4 o;
        o.x = pack_bf(acc[0], acc[1]);
        o.y = pack_bf(acc[2], acc[3]);
        o.z = pack_bf(acc[4], acc[5]);
        o.w = pack_bf(acc[6], acc[7]);
        ((uint4*)(g + (size_t)wid * D_DIM))[l32] = o;
    }
}

// ---------------------------------------------------------------------------
// GEMM: h' = relu(g @ W). BM=64 x BN=256 per block (4 waves, wave = 16 rows
// x all 256 cols). A hoisted to registers once (8 x short8/lane, shared by
// hi+lo planes via virtual K=512 = [W_hi; W_lo]). B staged through
// double-buffered LDS (2 x 32 KB k-chunks) with T2 XOR-swizzle
// (off ^= (n&7)<<4): 16 lanes reading 128B-stride rows at the same column
// would otherwise be a 16-way bank conflict. ReLU fused; bf16 or fp32 out.
// ---------------------------------------------------------------------------
__global__ void gemm_relu_kernel(const bf16_t* __restrict__ g,
                                 const bf16_t* __restrict__ Wt_hi,
                                 const bf16_t* __restrict__ Wt_lo,
                                 bf16_t* __restrict__ hdst, float* __restrict__ fdst) {
    __shared__ bf16_t Bs[2][256][64];        // 64 KB
    int tid  = threadIdx.x;
    int w    = tid >> 6;
    int lane = tid & 63;
    int quad = lane >> 4;
    int id16 = lane & 15;
    int bm   = blockIdx.x * 64 + w * 16;

    // hoist A: 8 k-fragments of this wave's 16 rows (row bm+id16)
    const bf16_t* arow = g + (size_t)(bm + id16) * D_DIM;
    short8 areg[8];
#pragma unroll
    for (int i = 0; i < 8; ++i)
        areg[i] = *(const short8*)(arow + i * 32 + quad * 8);

    f32x4 acc[16];
#pragma unroll
    for (int nt = 0; nt < 16; ++nt) acc[nt] = (f32x4){0.f, 0.f, 0.f, 0.f};

    char* bs = (char*)Bs;
    int seg = tid & 7;                       // 16B segment within 128B chunk-row

    // stage chunk 0
    {
        const bf16_t* src = Wt_hi;
#pragma unroll
        for (int pp = 0; pp < 8; ++pp) {
            int n = (tid >> 3) + pp * 32;
            unsigned off = (unsigned)(n * 128 + seg * 16) ^ (unsigned)((n & 7) << 4);
            *(uint4*)(bs + off) = *(const uint4*)(src + (size_t)n * D_DIM + seg * 8);
        }
    }
    __syncthreads();

    for (int c = 0; c < 8; ++c) {
        int buf = c & 1;
        if (c < 7) {                         // stage next chunk into other buffer
            int cn = c + 1;
            const bf16_t* src = (cn < 4) ? Wt_hi : Wt_lo;
            int ks = (cn & 3) * 64;
            unsigned bofs = (unsigned)((buf ^ 1) * 32768);
#pragma unroll
            for (int pp = 0; pp < 8; ++pp) {
                int n = (tid >> 3) + pp * 32;
                unsigned off = bofs + ((unsigned)(n * 128 + seg * 16) ^ (unsigned)((n & 7) << 4));
                *(uint4*)(bs + off) = *(const uint4*)(src + (size_t)n * D_DIM + ks + seg * 8);
            }
        }
        unsigned bofs = (unsigned)(buf * 32768);
#pragma unroll
        for (int kk2 = 0; kk2 < 2; ++kk2) {
            short8 a = areg[(c & 3) * 2 + kk2];
            unsigned kbyte = (unsigned)(kk2 * 64 + quad * 16);
#pragma unroll
            for (int nt = 0; nt < 16; ++nt) {
                int n = nt * 16 + id16;
                unsigned off = bofs + (((unsigned)(n * 128) + kbyte) ^ (unsigned)((n & 7) << 4));
                short8 bfr = *(const short8*)(bs + off);
                acc[nt] = __builtin_amdgcn_mfma_f32_16x16x32_bf16(a, bfr, acc[nt], 0, 0, 0);
            }
        }
        __syncthreads();
    }

    // epilogue: relu + store
#pragma unroll
    for (int nt = 0; nt < 16; ++nt) {
#pragma unroll
        for (int r = 0; r < 4; ++r) {
            int m = bm + quad * 4 + r;
            if (m < N_NODES) {
                float v = fmaxf(acc[nt][r], 0.f);
                int n = nt * 16 + id16;
                if (hdst) hdst[(size_t)m * D_DIM + n] = f2bf(v);
                else      fdst[(size_t)m * D_DIM + n] = v;
            }
        }
    }
}

extern "C" void kernel_launch(void* const* d_in, const int* in_sizes, int n_in,
                              void* d_out, int out_size, void* d_ws, size_t ws_size,
                              hipStream_t stream) {
    const float* init_m = (const float*)d_in[0];
    const int*   eidx   = (const int*)  d_in[1];
    const float* attr   = (const float*)d_in[2];
    const float* w1     = (const float*)d_in[3];
    const float* b1     = (const float*)d_in[4];
    const float* w2     = (const float*)d_in[5];
    const float* b2     = (const float*)d_in[6];
    const float* Wm     = (const float*)d_in[7];
    float* out = (float*)d_out;

    // Workspace layout (bytes, all offsets 256B-aligned):
    //   hbuf   @ 0          10,240,000   (h, bf16, 20000 rows)
    //   gbuf   @ 10,240,000 10,289,152   (g, bf16, 20096 rows: 96 pad rows for
    //                                     GEMM m-overread, zeroed once below)
    //   cnt    @ 20,529,152     80,000
    //   offs   @ 20,609,152     80,004
    //   cur    @ 20,689,408     80,000
    //   src_s  @ 20,769,408  2,560,000
    //   attr_s @ 23,329,408  2,560,000
    //   Wt_hi  @ 25,889,408    131,072
    //   Wt_lo  @ 26,020,480    131,072
    char* ws = (char*)d_ws;
    bf16_t* hbuf   = (bf16_t*)ws;
    bf16_t* gbuf   = (bf16_t*)(ws + 10240000);
    int*    cnt    = (int*)   (ws + 20529152);
    int*    offs   = (int*)   (ws + 20609152);
    int*    cur    = (int*)   (ws + 20689408);
    int*    src_s  = (int*)   (ws + 20769408);
    float*  attr_s = (float*) (ws + 23329408);
    bf16_t* Wt_hi  = (bf16_t*)(ws + 25889408);
    bf16_t* Wt_lo  = (bf16_t*)(ws + 26020480);

    // single memset covers gbuf pad rows (20,480,000..20,529,152) + cnt
    hipMemsetAsync(ws + 20480000, 0, 129152, stream);

    // front-end: h0 + edge-count + wsplit in one dispatch
    mega_kernel<<<N_NODES + 2500 + 256, 256, 0, stream>>>(
        init_m, w1, b1, w2, b2, hbuf, eidx, cnt, Wm, Wt_hi, Wt_lo);
    scan_kernel<<<1, 1024, 0, stream>>>(cnt, offs, cur);
    fill_kernel<<<(E_EDGES + 255) / 256, 256, 0, stream>>>(eidx, attr, cur, src_s, attr_s);

    // 3x GCN layer (reference order): g = gather(h); h' = relu(g @ W)
    dim3 ggrid((N_NODES * 64 + 255) / 256);
    dim3 mgrid((N_NODES + 63) / 64);
    for (int it = 0; it < 3; ++it) {
        gather_kernel<<<ggrid, 256, 0, stream>>>(hbuf, offs, src_s, attr_s, gbuf);
        if (it == 2)
            gemm_relu_kernel<<<mgrid, 256, 0, stream>>>(gbuf, Wt_hi, Wt_lo,
                                                        (bf16_t*)nullptr, out);
        else
            gemm_relu_kernel<<<mgrid, 256, 0, stream>>>(gbuf, Wt_hi, Wt_lo,
                                                        hbuf, (float*)nullptr);
    }
}